// Round 6
// baseline (169.923 us; speedup 1.0000x reference)
//
#include <hip/hip_runtime.h>
#include <hip/hip_bf16.h>
#include <stdint.h>

#define SEQ 2048
#define HID 2048
#define NH 16
#define HD 128
// 1/sqrt(128) * log2(e): softmax runs in exp2 domain
#define QSCALE_L2E 0.1275304429019769f

typedef __attribute__((ext_vector_type(4))) float f32x4;
typedef __attribute__((ext_vector_type(8))) short short8;
typedef __attribute__((ext_vector_type(4))) float f4;
typedef __attribute__((ext_vector_type(4))) unsigned short us4;

__device__ __forceinline__ unsigned short f2bu(float f) {
  union { float f; unsigned int u; } c; c.f = f;
  unsigned int u = c.u + 0x7fffu + ((c.u >> 16) & 1u);  // RNE, finite inputs
  return (unsigned short)(u >> 16);
}

__device__ __forceinline__ unsigned short f2bu_fast(float f) {
  union { float f; unsigned int u; } c; c.f = f;
  return (unsigned short)((c.u + 0x8000u) >> 16);
}

__device__ __forceinline__ float b2f(unsigned short u) {
  union { unsigned int u; float f; } c; c.u = ((unsigned int)u) << 16; return c.f;
}

__device__ __forceinline__ float exp2fast(float x) {
  float r; asm("v_exp_f32 %0, %1" : "=v"(r) : "v"(x)); return r;
}

__device__ __forceinline__ void gload_lds16(const void* g, void* l) {
  __builtin_amdgcn_global_load_lds((const __attribute__((address_space(1))) void*)g,
                                   (__attribute__((address_space(3))) void*)l, 16, 0, 0);
}

#define BAR() __builtin_amdgcn_s_barrier()
#define LGKM0() do { asm volatile("s_waitcnt lgkmcnt(0)" ::: "memory"); __builtin_amdgcn_sched_barrier(0); } while (0)
#define VM6()   do { asm volatile("s_waitcnt vmcnt(6)"   ::: "memory"); __builtin_amdgcn_sched_barrier(0); } while (0)
#define VM0()   do { asm volatile("s_waitcnt vmcnt(0)"   ::: "memory"); __builtin_amdgcn_sched_barrier(0); } while (0)

// ---------------- fp32 -> bf16 convert, 5 equal-size arrays (32B/thread) ----
__global__ __launch_bounds__(256) void cvt_kernel(
    const float* __restrict__ s0, const float* __restrict__ s1,
    const float* __restrict__ s2, const float* __restrict__ s3,
    const float* __restrict__ s4,
    unsigned short* __restrict__ d0, unsigned short* __restrict__ d1,
    unsigned short* __restrict__ d2, unsigned short* __restrict__ d3,
    unsigned short* __restrict__ d4, int n)
{
  const float* s; unsigned short* d;
  switch (blockIdx.y) {
    case 0: s = s0; d = d0; break;
    case 1: s = s1; d = d1; break;
    case 2: s = s2; d = d2; break;
    case 3: s = s3; d = d3; break;
    default: s = s4; d = d4; break;
  }
  const int stride = gridDim.x * blockDim.x;
  for (int i = blockIdx.x * blockDim.x + threadIdx.x; i * 8 < n; i += stride) {
    f4 v0 = *(const f4*)&s[i * 8];
    f4 v1 = *(const f4*)&s[i * 8 + 4];
    short8 o;
    o[0] = (short)f2bu(v0[0]); o[1] = (short)f2bu(v0[1]);
    o[2] = (short)f2bu(v0[2]); o[3] = (short)f2bu(v0[3]);
    o[4] = (short)f2bu(v1[0]); o[5] = (short)f2bu(v1[1]);
    o[6] = (short)f2bu(v1[2]); o[7] = (short)f2bu(v1[3]);
    *(short8*)&d[i * 8] = o;
  }
}

// ---------------- 128x128 bf16 GEMM, m97-style single-buffer ----------------
// R18-verified WIN (QKV 77 -> ~50us): BM=BN=128, BK=64, 4 waves (2Mx2N),
// per-wave 64x64 (acc[4][4]). SINGLE 32KB LDS buffer + launch_bounds(256,3)
// -> 3 blocks/CU; the per-tile vmcnt(0)+barrier drain is covered by the
// OTHER resident blocks (m114 cross-block MFMA/staging overlap).
template<int MODE>
__global__ __launch_bounds__(256, 3) void gemm97(
    const unsigned short* __restrict__ A,
    const unsigned short* __restrict__ B,
    const float* __restrict__ b0, const float* __restrict__ b1, const float* __restrict__ b2,
    unsigned short* __restrict__ O0, unsigned short* __restrict__ O1, unsigned short* __restrict__ O2,
    float* __restrict__ Of, int M, int N, int K)
{
  extern __shared__ unsigned short lds[];  // A[128*64] @0, B[128*64] @8192 el
  const int tid = threadIdx.x;
  const int lane = tid & 63, w = tid >> 6;
  const int g = lane >> 4, q = lane & 15;
  const int wgM = w >> 1, wgN = w & 1;     // 2M x 2N wave grid
  const long bm = (long)blockIdx.y * 128, bn = (long)blockIdx.x * 128;
  const int NK = K >> 6;

  // staging lane geometry (proven): lane writes LDS row (l>>3), 16B-block
  // (l&7); global column block pre-swizzled: (l&7)^(l>>3)
  const int srl = lane >> 3;
  const int scE = ((lane & 7) ^ srl) * 8;
  // fragment read swizzle: logical k-block g of row r stored at g^(r&7);
  // all frag rows have row&7 == q&7
  const int c0 = (g ^ (q & 7)) * 8;
  const int c1 = c0 ^ 32;
  const int aB = (wgM * 64 + q) * 64;
  const int bB = (wgN * 64 + q) * 64;

  f32x4 acc[4][4] = {};
  short8 a[4][2], b[4][2];

#define STAGE(gp, gbase, jj, ldsOff) do {                                     \
    _Pragma("unroll")                                                         \
    for (int c_ = 0; c_ < 4; ++c_) {                                          \
      const long row_ = (c_ * 4 + w) * 8 + srl;                               \
      gload_lds16(&(gp)[((gbase) + row_) * (long)K + (jj) * 64 + scE],        \
                  &lds[(ldsOff) + (c_ * 4 + w) * 512]);                       \
    }                                                                         \
  } while (0)

#define QUADD(n0, n1)                                                         \
  do {                                                                        \
    __builtin_amdgcn_s_setprio(1);                                            \
    _Pragma("unroll")                                                         \
    for (int mi_ = 0; mi_ < 4; ++mi_) {                                       \
      acc[mi_][n0] = __builtin_amdgcn_mfma_f32_16x16x32_bf16(                 \
          a[mi_][0], b[n0][0], acc[mi_][n0], 0, 0, 0);                        \
      acc[mi_][n0] = __builtin_amdgcn_mfma_f32_16x16x32_bf16(                 \
          a[mi_][1], b[n0][1], acc[mi_][n0], 0, 0, 0);                        \
      acc[mi_][n1] = __builtin_amdgcn_mfma_f32_16x16x32_bf16(                 \
          a[mi_][0], b[n1][0], acc[mi_][n1], 0, 0, 0);                        \
      acc[mi_][n1] = __builtin_amdgcn_mfma_f32_16x16x32_bf16(                 \
          a[mi_][1], b[n1][1], acc[mi_][n1], 0, 0, 0);                        \
    }                                                                         \
    __builtin_amdgcn_s_setprio(0);                                            \
  } while (0)

  for (int j = 0; j < NK; ++j) {
    STAGE(A, bm, j, 0);
    STAGE(B, bn, j, 8192);
    VM0();                                  // tile landed
    BAR();                                  // all waves see full tile
#pragma unroll
    for (int mi = 0; mi < 4; ++mi) {
      a[mi][0] = *(const short8*)&lds[aB + mi * 1024 + c0];
      a[mi][1] = *(const short8*)&lds[aB + mi * 1024 + c1];
    }
#pragma unroll
    for (int ni = 0; ni < 4; ++ni) {
      b[ni][0] = *(const short8*)&lds[8192 + bB + ni * 1024 + c0];
      b[ni][1] = *(const short8*)&lds[8192 + bB + ni * 1024 + c1];
    }
    QUADD(0, 1);
    QUADD(2, 3);
    BAR();                                  // all reads done -> safe to restage
  }

#pragma unroll
  for (int ni = 0; ni < 4; ++ni) {
    const int col = (int)bn + wgN * 64 + ni * 16 + q;
    float bv;
    if (MODE == 4) {
      const int which = col >> 11, c = col & 2047;
      const float* bp = which == 0 ? b0 : (which == 1 ? b1 : b2);
      bv = bp[c];
    } else {
      bv = b0[col];
    }
#pragma unroll
    for (int mi = 0; mi < 4; ++mi)
#pragma unroll
      for (int r = 0; r < 4; ++r) {
        const long row = bm + wgM * 64 + mi * 16 + 4 * g + r;
        const float v = acc[mi][ni][r] + bv;
        if (MODE == 4) {
          const int which = col >> 11, c = col & 2047, head = c >> 7, d = c & 127;
          if (which == 0)      O0[((long)head * SEQ + row) * HD + d] = f2bu(v * QSCALE_L2E);
          else if (which == 1) O1[((long)head * SEQ + row) * HD + d] = f2bu(v);
          else                 O2[((long)head * HD + d) * SEQ + row] = f2bu(v);
        } else {
          Of[row * (long)N + col] = v;
        }
      }
  }
#undef STAGE
#undef QUADD
}

// ---------------- 64x128 bf16 GEMM  C = A[M,K] * B[N,K]^T + bias ------------
// Kept for out-projection (grid 16x32 = 512 blocks; the 128^2 kernel would be
// 256 blocks = 1 block/CU -> no cross-block overlap).
template<int MODE>
__global__ __launch_bounds__(256, 2) void gemm128(
    const unsigned short* __restrict__ A,
    const unsigned short* __restrict__ B,
    const float* __restrict__ b0, const float* __restrict__ b1, const float* __restrict__ b2,
    unsigned short* __restrict__ O0, unsigned short* __restrict__ O1, unsigned short* __restrict__ O2,
    float* __restrict__ Of, int M, int N, int K)
{
  constexpr int ASZ = 64 * 64;
  constexpr int BSZ = 128 * 64;

  extern __shared__ unsigned short lds[];
  const int tid = threadIdx.x;
  const int lane = tid & 63, w = tid >> 6;
  const int g = lane >> 4, q = lane & 15;
  const long bm = (long)blockIdx.y * 64, bn = (long)blockIdx.x * 128;
  const int NK = K >> 6;

  const int srl = lane >> 3;
  const int scE = ((lane & 7) ^ srl) * 8;
  const int c0 = (g ^ (q & 7)) * 8;
  const int c1 = c0 ^ 32;
  const int aB = q * 64;
  const int bB = (w * 32 + q) * 64;

  f32x4 acc[4][2] = {};
  short8 a[4][2], b[2][2];

#define STAGE_A(jj) do {                                                      \
    unsigned short* dst_ = lds + (((jj) & 1) ? ASZ : 0);                      \
    _Pragma("unroll")                                                         \
    for (int c_ = 0; c_ < 2; ++c_) {                                          \
      const long row_ = (c_ * 4 + w) * 8 + srl;                               \
      gload_lds16(&A[(bm + row_) * (long)K + (jj) * 64 + scE],                \
                  &dst_[(c_ * 4 + w) * 512]);                                 \
    }                                                                         \
  } while (0)

#define STAGE_B(jj) do {                                                      \
    unsigned short* dst_ = lds + 2 * ASZ + (((jj) & 1) ? BSZ : 0);            \
    _Pragma("unroll")                                                         \
    for (int c_ = 0; c_ < 4; ++c_) {                                          \
      const long row_ = (c_ * 4 + w) * 8 + srl;                               \
      gload_lds16(&B[(bn + row_) * (long)K + (jj) * 64 + scE],                \
                  &dst_[(c_ * 4 + w) * 512]);                                 \
    }                                                                         \
  } while (0)

#define QUAD8(ni)                                                             \
  do {                                                                        \
    __builtin_amdgcn_s_setprio(1);                                            \
    _Pragma("unroll")                                                         \
    for (int mi_ = 0; mi_ < 4; ++mi_) {                                       \
      acc[mi_][ni] = __builtin_amdgcn_mfma_f32_16x16x32_bf16(                 \
          a[mi_][0], b[ni][0], acc[mi_][ni], 0, 0, 0);                        \
      acc[mi_][ni] = __builtin_amdgcn_mfma_f32_16x16x32_bf16(                 \
          a[mi_][1], b[ni][1], acc[mi_][ni], 0, 0, 0);                        \
    }                                                                         \
    __builtin_amdgcn_s_setprio(0);                                            \
  } while (0)

  STAGE_A(0); STAGE_B(0);
  STAGE_A(1); STAGE_B(1);
  VM6();
  BAR();

  for (int j = 0; j < NK; ++j) {
    unsigned short* At = lds + ((j & 1) ? ASZ : 0);
    unsigned short* Bt = lds + 2 * ASZ + ((j & 1) ? BSZ : 0);

#pragma unroll
    for (int mi = 0; mi < 4; ++mi) {
      a[mi][0] = *(const short8*)&At[aB + mi * 1024 + c0];
      a[mi][1] = *(const short8*)&At[aB + mi * 1024 + c1];
    }
#pragma unroll
    for (int ni = 0; ni < 2; ++ni) {
      b[ni][0] = *(const short8*)&Bt[bB + ni * 1024 + c0];
      b[ni][1] = *(const short8*)&Bt[bB + ni * 1024 + c1];
    }
    QUAD8(0);
    LGKM0();
    BAR();                                  // (a)
    if (j + 2 < NK) { STAGE_A(j + 2); STAGE_B(j + 2); }
    QUAD8(1);
    if (j < NK - 2) { VM6(); } else { VM0(); }
    BAR();                                  // (b)
  }

#pragma unroll
  for (int ni = 0; ni < 2; ++ni) {
    const int col = (int)bn + w * 32 + ni * 16 + q;
    float bv;
    if (MODE == 4) {
      const int which = col >> 11, c = col & 2047;
      const float* bp = which == 0 ? b0 : (which == 1 ? b1 : b2);
      bv = bp[c];
    } else {
      bv = b0[col];
    }
#pragma unroll
    for (int mi = 0; mi < 4; ++mi)
#pragma unroll
      for (int r = 0; r < 4; ++r) {
        const long row = bm + mi * 16 + 4 * g + r;
        const float v = acc[mi][ni][r] + bv;
        if (MODE == 4) {
          const int which = col >> 11, c = col & 2047, head = c >> 7, d = c & 127;
          if (which == 0)      O0[((long)head * SEQ + row) * HD + d] = f2bu(v * QSCALE_L2E);
          else if (which == 1) O1[((long)head * SEQ + row) * HD + d] = f2bu(v);
          else                 O2[((long)head * HD + d) * SEQ + row] = f2bu(v);
        } else {
          Of[row * (long)N + col] = v;
        }
      }
  }
#undef STAGE_A
#undef STAGE_B
#undef QUAD8
}

// ---------------- flash attention v8: KVB=32 for occupancy ------------------
// R20: R19 falsified "KV-miss-latency-bound" (FETCH 69.7->12.3MB, dur -2.3us
// only). Profile (Mfma 20%, VALU 22%, occ 19%) says latency-bound at 2
// waves/SIMD: the per-tile serial chain can't be hidden. KVB 64->32 shrinks
// LDS 40KB->20KB (Kt 8K + Vt 8K + Pt 4K) -> ~5 blocks/CU (VGPR-capped)
// = ~20 waves/CU, 2.5-3x TLP. Per-tile work halves; total unchanged.
// Pt swizzle fixed: XOR with (row>>2)^(row&3) (lane-varying g^r on write)
// instead of row&3 (wave-uniform -> was 4-way conflicted, 4.19M cycles).
#define KVB 32
__global__ __launch_bounds__(256) void flash_attn(
    const unsigned short* __restrict__ Qb,
    const unsigned short* __restrict__ Kb,
    const unsigned short* __restrict__ VTb,
    unsigned short* __restrict__ attnb)      // [SEQ][HID] bf16
{
  __shared__ __align__(16) unsigned short Kt[32 * 128];    // 8KB
  __shared__ __align__(16) unsigned short Vt[128 * 32];    // 8KB
  __shared__ __align__(16) unsigned short Pt[4][16 * 32];  // 4KB
  const int tid = threadIdx.x;
  const int l = tid & 63, w = tid >> 6;
  const int g = l >> 4, q = l & 15;
  const int bid = blockIdx.x;
  const int jj = bid >> 3;
  const int h = ((bid & 7) << 1) | (jj >> 5);   // 2 heads per XCD (R19-proven)
  const int qb = jj & 31;
  const int qrow0 = qb * 64 + w * 16;

  short8 qf[4];
#pragma unroll
  for (int dc = 0; dc < 4; ++dc)
    qf[dc] = *(const short8*)&Qb[((long)h * SEQ + qrow0 + q) * HD + dc * 32 + g * 8];

  f32x4 oacc[8] = {};
  float lsum[4] = {0.f, 0.f, 0.f, 0.f};

  const int kr = tid >> 4, kc16 = tid & 15;   // K stage: rows kr+16*it
  const int vr = tid >> 2, vc4 = tid & 3;     // V stage: rows vr+64*it
  const unsigned short* Kg = Kb + (long)h * SEQ * HD;
  const unsigned short* Vg = VTb + (long)h * HD * SEQ;

  short8 kreg[2], vreg[2];
#pragma unroll
  for (int it = 0; it < 2; ++it) {
    kreg[it] = *(const short8*)&Kg[(long)(kr + it * 16) * HD + kc16 * 8];
    vreg[it] = *(const short8*)&Vg[(long)(vr + it * 64) * SEQ + vc4 * 8];
  }

  for (int kb = 0; kb < SEQ; kb += KVB) {
    __syncthreads();
#pragma unroll
    for (int it = 0; it < 2; ++it) {
      const int krow = kr + it * 16;
      *(short8*)&Kt[((krow * 256 + kc16 * 16) ^ ((krow & 7) << 4)) >> 1] = kreg[it];
      const int vrow = vr + it * 64;
      *(short8*)&Vt[(vrow * 64 + ((vc4 ^ (vrow & 3)) << 4)) >> 1] = vreg[it];
    }
    __syncthreads();
    if (kb + KVB < SEQ) {
#pragma unroll
      for (int it = 0; it < 2; ++it) {
        kreg[it] = *(const short8*)&Kg[(long)(kb + KVB + kr + it * 16) * HD + kc16 * 8];
        vreg[it] = *(const short8*)&Vg[(long)(vr + it * 64) * SEQ + kb + KVB + vc4 * 8];
      }
    }

    f32x4 sacc[2] = {};
    __builtin_amdgcn_s_setprio(1);
#pragma unroll
    for (int kc = 0; kc < 2; ++kc) {
      const int krow = kc * 16 + q;
      const int sw = (krow & 7) << 4;
#pragma unroll
      for (int dc = 0; dc < 4; ++dc) {
        short8 kf = *(const short8*)&Kt[((krow * 256 + dc * 64 + g * 16) ^ sw) >> 1];
        sacc[kc] = __builtin_amdgcn_mfma_f32_16x16x32_bf16(qf[dc], kf, sacc[kc], 0, 0, 0);
      }
    }
    __builtin_amdgcn_s_setprio(0);

    float p[2][4];
#pragma unroll
    for (int r = 0; r < 4; ++r) {
#pragma unroll
      for (int kc = 0; kc < 2; ++kc) p[kc][r] = exp2fast(sacc[kc][r]);
      lsum[r] += p[0][r] + p[1][r];
    }

    // Pt: [16 rows][32 cols] per wave, 64B rows = 4 x 16B blocks.
    // Stored block = logical ^ ((row>>2)^(row&3))  (lane-varying on write).
    unsigned short* Pw = &Pt[w][0];
#pragma unroll
    for (int r = 0; r < 4; ++r) {
      const int prow = 4 * g + r;
      const int px = g ^ r;                  // (prow>>2)^(prow&3)
#pragma unroll
      for (int kc = 0; kc < 2; ++kc) {
        const int blk = kc * 2 + (q >> 3);
        Pw[(prow * 64 + (((blk ^ px) << 4) | ((q & 7) * 2))) >> 1] = f2bu_fast(p[kc][r]);
      }
    }

    const int rx = (q >> 2) ^ (q & 3);
    short8 pf = *(const short8*)&Pw[(q * 64 + ((g ^ rx) << 4)) >> 1];

    __builtin_amdgcn_s_setprio(1);
#pragma unroll
    for (int dt = 0; dt < 8; ++dt) {
      const int vrow = dt * 16 + q;
      short8 vf = *(const short8*)&Vt[(vrow * 64 + ((g ^ (q & 3)) << 4)) >> 1];
      oacc[dt] = __builtin_amdgcn_mfma_f32_16x16x32_bf16(pf, vf, oacc[dt], 0, 0, 0);
    }
    __builtin_amdgcn_s_setprio(0);
  }

  // sum exp over the 16 q-lanes (KV columns live on q within each 16-lane grp)
#pragma unroll
  for (int off = 1; off < 16; off <<= 1)
#pragma unroll
    for (int r = 0; r < 4; ++r) lsum[r] += __shfl_xor(lsum[r], off);

  const float rl0 = 1.f / lsum[0], rl1 = 1.f / lsum[1];
  const float rl2 = 1.f / lsum[2], rl3 = 1.f / lsum[3];
#pragma unroll
  for (int dt = 0; dt < 8; ++dt) {
    const long colb = (long)h * HD + dt * 16 + q;
    attnb[(long)(qrow0 + 4 * g + 0) * HID + colb] = f2bu(oacc[dt][0] * rl0);
    attnb[(long)(qrow0 + 4 * g + 1) * HID + colb] = f2bu(oacc[dt][1] * rl1);
    attnb[(long)(qrow0 + 4 * g + 2) * HID + colb] = f2bu(oacc[dt][2] * rl2);
    attnb[(long)(qrow0 + 4 * g + 3) * HID + colb] = f2bu(oacc[dt][3] * rl3);
  }
}

extern "C" void kernel_launch(void* const* d_in, const int* in_sizes, int n_in,
                              void* d_out, int out_size, void* d_ws, size_t ws_size,
                              hipStream_t stream)
{
  const float* x  = (const float*)d_in[0];
  const float* wq = (const float*)d_in[1];
  const float* bq = (const float*)d_in[2];
  const float* wk = (const float*)d_in[3];
  const float* bk = (const float*)d_in[4];
  const float* wv = (const float*)d_in[5];
  const float* bv = (const float*)d_in[6];
  const float* wo = (const float*)d_in[7];
  const float* bo = (const float*)d_in[8];

  const long NEL = (long)HID * HID;
  unsigned short* Xb   = (unsigned short*)d_ws;
  unsigned short* Wqkv = Xb + NEL;
  unsigned short* Wob  = Wqkv + 3 * NEL;
  unsigned short* Qbuf = Wob + NEL;
  unsigned short* Kbuf = Qbuf + NEL;
  unsigned short* VTb  = Kbuf + NEL;
  unsigned short* Attn = VTb + NEL;

  cvt_kernel<<<dim3(512, 5), 256, 0, stream>>>(
      x, wq, wk, wv, wo, Xb, Wqkv, Wqkv + NEL, Wqkv + 2 * NEL, Wob, (int)NEL);

  gemm97<4><<<dim3(48, 16), 256, 32768, stream>>>(
      Xb, Wqkv, bq, bk, bv, Qbuf, Kbuf, VTb, nullptr, SEQ, 3 * HID, HID);

  flash_attn<<<dim3(512), 256, 0, stream>>>(Qbuf, Kbuf, VTb, Attn);

  gemm128<3><<<dim3(16, 32), 256, 49152, stream>>>(
      Attn, Wob, bo, nullptr, nullptr, nullptr, nullptr, nullptr,
      (float*)d_out, SEQ, HID, HID);
}

// Round 8
// 163.982 us; speedup vs baseline: 1.0362x; 1.0362x over previous
//
#include <hip/hip_runtime.h>
#include <hip/hip_bf16.h>
#include <stdint.h>

#define SEQ 2048
#define HID 2048
#define NH 16
#define HD 128
// 1/sqrt(128) * log2(e): softmax runs in exp2 domain
#define QSCALE_L2E 0.1275304429019769f

typedef __attribute__((ext_vector_type(4))) float f32x4;
typedef __attribute__((ext_vector_type(8))) short short8;
typedef __attribute__((ext_vector_type(4))) float f4;
typedef __attribute__((ext_vector_type(4))) unsigned short us4;

__device__ __forceinline__ unsigned short f2bu(float f) {
  union { float f; unsigned int u; } c; c.f = f;
  unsigned int u = c.u + 0x7fffu + ((c.u >> 16) & 1u);  // RNE, finite inputs
  return (unsigned short)(u >> 16);
}

__device__ __forceinline__ unsigned short f2bu_fast(float f) {
  union { float f; unsigned int u; } c; c.f = f;
  return (unsigned short)((c.u + 0x8000u) >> 16);
}

__device__ __forceinline__ float b2f(unsigned short u) {
  union { unsigned int u; float f; } c; c.u = ((unsigned int)u) << 16; return c.f;
}

__device__ __forceinline__ float exp2fast(float x) {
  float r; asm("v_exp_f32 %0, %1" : "=v"(r) : "v"(x)); return r;
}

__device__ __forceinline__ void gload_lds16(const void* g, void* l) {
  __builtin_amdgcn_global_load_lds((const __attribute__((address_space(1))) void*)g,
                                   (__attribute__((address_space(3))) void*)l, 16, 0, 0);
}

#define BAR() __builtin_amdgcn_s_barrier()
#define LGKM0() do { asm volatile("s_waitcnt lgkmcnt(0)" ::: "memory"); __builtin_amdgcn_sched_barrier(0); } while (0)
#define VM6()   do { asm volatile("s_waitcnt vmcnt(6)"   ::: "memory"); __builtin_amdgcn_sched_barrier(0); } while (0)
#define VM0()   do { asm volatile("s_waitcnt vmcnt(0)"   ::: "memory"); __builtin_amdgcn_sched_barrier(0); } while (0)

// ---------------- fp32 -> bf16 convert, 5 equal-size arrays (32B/thread) ----
__global__ __launch_bounds__(256) void cvt_kernel(
    const float* __restrict__ s0, const float* __restrict__ s1,
    const float* __restrict__ s2, const float* __restrict__ s3,
    const float* __restrict__ s4,
    unsigned short* __restrict__ d0, unsigned short* __restrict__ d1,
    unsigned short* __restrict__ d2, unsigned short* __restrict__ d3,
    unsigned short* __restrict__ d4, int n)
{
  const float* s; unsigned short* d;
  switch (blockIdx.y) {
    case 0: s = s0; d = d0; break;
    case 1: s = s1; d = d1; break;
    case 2: s = s2; d = d2; break;
    case 3: s = s3; d = d3; break;
    default: s = s4; d = d4; break;
  }
  const int stride = gridDim.x * blockDim.x;
  for (int i = blockIdx.x * blockDim.x + threadIdx.x; i * 8 < n; i += stride) {
    f4 v0 = *(const f4*)&s[i * 8];
    f4 v1 = *(const f4*)&s[i * 8 + 4];
    short8 o;
    o[0] = (short)f2bu(v0[0]); o[1] = (short)f2bu(v0[1]);
    o[2] = (short)f2bu(v0[2]); o[3] = (short)f2bu(v0[3]);
    o[4] = (short)f2bu(v1[0]); o[5] = (short)f2bu(v1[1]);
    o[6] = (short)f2bu(v1[2]); o[7] = (short)f2bu(v1[3]);
    *(short8*)&d[i * 8] = o;
  }
}

// ---------------- 128x128 bf16 GEMM, m97-style single-buffer ----------------
// R18-verified WIN (QKV 77 -> ~50us): BM=BN=128, BK=64, 4 waves (2Mx2N),
// per-wave 64x64 (acc[4][4]). SINGLE 32KB LDS buffer + launch_bounds(256,3)
// -> 3 blocks/CU; the per-tile vmcnt(0)+barrier drain is covered by the
// OTHER resident blocks (m114 cross-block MFMA/staging overlap).
template<int MODE>
__global__ __launch_bounds__(256, 3) void gemm97(
    const unsigned short* __restrict__ A,
    const unsigned short* __restrict__ B,
    const float* __restrict__ b0, const float* __restrict__ b1, const float* __restrict__ b2,
    unsigned short* __restrict__ O0, unsigned short* __restrict__ O1, unsigned short* __restrict__ O2,
    float* __restrict__ Of, int M, int N, int K)
{
  extern __shared__ unsigned short lds[];  // A[128*64] @0, B[128*64] @8192 el
  const int tid = threadIdx.x;
  const int lane = tid & 63, w = tid >> 6;
  const int g = lane >> 4, q = lane & 15;
  const int wgM = w >> 1, wgN = w & 1;     // 2M x 2N wave grid
  const long bm = (long)blockIdx.y * 128, bn = (long)blockIdx.x * 128;
  const int NK = K >> 6;

  // staging lane geometry (proven): lane writes LDS row (l>>3), 16B-block
  // (l&7); global column block pre-swizzled: (l&7)^(l>>3)
  const int srl = lane >> 3;
  const int scE = ((lane & 7) ^ srl) * 8;
  // fragment read swizzle: logical k-block g of row r stored at g^(r&7);
  // all frag rows have row&7 == q&7
  const int c0 = (g ^ (q & 7)) * 8;
  const int c1 = c0 ^ 32;
  const int aB = (wgM * 64 + q) * 64;
  const int bB = (wgN * 64 + q) * 64;

  f32x4 acc[4][4] = {};
  short8 a[4][2], b[4][2];

#define STAGE(gp, gbase, jj, ldsOff) do {                                     \
    _Pragma("unroll")                                                         \
    for (int c_ = 0; c_ < 4; ++c_) {                                          \
      const long row_ = (c_ * 4 + w) * 8 + srl;                               \
      gload_lds16(&(gp)[((gbase) + row_) * (long)K + (jj) * 64 + scE],        \
                  &lds[(ldsOff) + (c_ * 4 + w) * 512]);                       \
    }                                                                         \
  } while (0)

#define QUADD(n0, n1)                                                         \
  do {                                                                        \
    __builtin_amdgcn_s_setprio(1);                                            \
    _Pragma("unroll")                                                         \
    for (int mi_ = 0; mi_ < 4; ++mi_) {                                       \
      acc[mi_][n0] = __builtin_amdgcn_mfma_f32_16x16x32_bf16(                 \
          a[mi_][0], b[n0][0], acc[mi_][n0], 0, 0, 0);                        \
      acc[mi_][n0] = __builtin_amdgcn_mfma_f32_16x16x32_bf16(                 \
          a[mi_][1], b[n0][1], acc[mi_][n0], 0, 0, 0);                        \
      acc[mi_][n1] = __builtin_amdgcn_mfma_f32_16x16x32_bf16(                 \
          a[mi_][0], b[n1][0], acc[mi_][n1], 0, 0, 0);                        \
      acc[mi_][n1] = __builtin_amdgcn_mfma_f32_16x16x32_bf16(                 \
          a[mi_][1], b[n1][1], acc[mi_][n1], 0, 0, 0);                        \
    }                                                                         \
    __builtin_amdgcn_s_setprio(0);                                            \
  } while (0)

  for (int j = 0; j < NK; ++j) {
    STAGE(A, bm, j, 0);
    STAGE(B, bn, j, 8192);
    VM0();                                  // tile landed
    BAR();                                  // all waves see full tile
#pragma unroll
    for (int mi = 0; mi < 4; ++mi) {
      a[mi][0] = *(const short8*)&lds[aB + mi * 1024 + c0];
      a[mi][1] = *(const short8*)&lds[aB + mi * 1024 + c1];
    }
#pragma unroll
    for (int ni = 0; ni < 4; ++ni) {
      b[ni][0] = *(const short8*)&lds[8192 + bB + ni * 1024 + c0];
      b[ni][1] = *(const short8*)&lds[8192 + bB + ni * 1024 + c1];
    }
    QUADD(0, 1);
    QUADD(2, 3);
    BAR();                                  // all reads done -> safe to restage
  }

#pragma unroll
  for (int ni = 0; ni < 4; ++ni) {
    const int col = (int)bn + wgN * 64 + ni * 16 + q;
    float bv;
    if (MODE == 4) {
      const int which = col >> 11, c = col & 2047;
      const float* bp = which == 0 ? b0 : (which == 1 ? b1 : b2);
      bv = bp[c];
    } else {
      bv = b0[col];
    }
#pragma unroll
    for (int mi = 0; mi < 4; ++mi)
#pragma unroll
      for (int r = 0; r < 4; ++r) {
        const long row = bm + wgM * 64 + mi * 16 + 4 * g + r;
        const float v = acc[mi][ni][r] + bv;
        if (MODE == 4) {
          const int which = col >> 11, c = col & 2047, head = c >> 7, d = c & 127;
          if (which == 0)      O0[((long)head * SEQ + row) * HD + d] = f2bu(v * QSCALE_L2E);
          else if (which == 1) O1[((long)head * SEQ + row) * HD + d] = f2bu(v);
          else                 O2[((long)head * HD + d) * SEQ + row] = f2bu(v);
        } else {
          Of[row * (long)N + col] = v;
        }
      }
  }
#undef STAGE
#undef QUADD
}

// ---------------- 64x128 bf16 GEMM  C = A[M,K] * B[N,K]^T + bias ------------
// Kept for out-projection (grid 16x32 = 512 blocks; the 128^2 kernel would be
// 256 blocks = 1 block/CU -> no cross-block overlap).
template<int MODE>
__global__ __launch_bounds__(256, 2) void gemm128(
    const unsigned short* __restrict__ A,
    const unsigned short* __restrict__ B,
    const float* __restrict__ b0, const float* __restrict__ b1, const float* __restrict__ b2,
    unsigned short* __restrict__ O0, unsigned short* __restrict__ O1, unsigned short* __restrict__ O2,
    float* __restrict__ Of, int M, int N, int K)
{
  constexpr int ASZ = 64 * 64;
  constexpr int BSZ = 128 * 64;

  extern __shared__ unsigned short lds[];
  const int tid = threadIdx.x;
  const int lane = tid & 63, w = tid >> 6;
  const int g = lane >> 4, q = lane & 15;
  const long bm = (long)blockIdx.y * 64, bn = (long)blockIdx.x * 128;
  const int NK = K >> 6;

  const int srl = lane >> 3;
  const int scE = ((lane & 7) ^ srl) * 8;
  const int c0 = (g ^ (q & 7)) * 8;
  const int c1 = c0 ^ 32;
  const int aB = q * 64;
  const int bB = (w * 32 + q) * 64;

  f32x4 acc[4][2] = {};
  short8 a[4][2], b[2][2];

#define STAGE_A(jj) do {                                                      \
    unsigned short* dst_ = lds + (((jj) & 1) ? ASZ : 0);                      \
    _Pragma("unroll")                                                         \
    for (int c_ = 0; c_ < 2; ++c_) {                                          \
      const long row_ = (c_ * 4 + w) * 8 + srl;                               \
      gload_lds16(&A[(bm + row_) * (long)K + (jj) * 64 + scE],                \
                  &dst_[(c_ * 4 + w) * 512]);                                 \
    }                                                                         \
  } while (0)

#define STAGE_B(jj) do {                                                      \
    unsigned short* dst_ = lds + 2 * ASZ + (((jj) & 1) ? BSZ : 0);            \
    _Pragma("unroll")                                                         \
    for (int c_ = 0; c_ < 4; ++c_) {                                          \
      const long row_ = (c_ * 4 + w) * 8 + srl;                               \
      gload_lds16(&B[(bn + row_) * (long)K + (jj) * 64 + scE],                \
                  &dst_[(c_ * 4 + w) * 512]);                                 \
    }                                                                         \
  } while (0)

#define QUAD8(ni)                                                             \
  do {                                                                        \
    __builtin_amdgcn_s_setprio(1);                                            \
    _Pragma("unroll")                                                         \
    for (int mi_ = 0; mi_ < 4; ++mi_) {                                       \
      acc[mi_][ni] = __builtin_amdgcn_mfma_f32_16x16x32_bf16(                 \
          a[mi_][0], b[ni][0], acc[mi_][ni], 0, 0, 0);                        \
      acc[mi_][ni] = __builtin_amdgcn_mfma_f32_16x16x32_bf16(                 \
          a[mi_][1], b[ni][1], acc[mi_][ni], 0, 0, 0);                        \
    }                                                                         \
    __builtin_amdgcn_s_setprio(0);                                            \
  } while (0)

  STAGE_A(0); STAGE_B(0);
  STAGE_A(1); STAGE_B(1);
  VM6();
  BAR();

  for (int j = 0; j < NK; ++j) {
    unsigned short* At = lds + ((j & 1) ? ASZ : 0);
    unsigned short* Bt = lds + 2 * ASZ + ((j & 1) ? BSZ : 0);

#pragma unroll
    for (int mi = 0; mi < 4; ++mi) {
      a[mi][0] = *(const short8*)&At[aB + mi * 1024 + c0];
      a[mi][1] = *(const short8*)&At[aB + mi * 1024 + c1];
    }
#pragma unroll
    for (int ni = 0; ni < 2; ++ni) {
      b[ni][0] = *(const short8*)&Bt[bB + ni * 1024 + c0];
      b[ni][1] = *(const short8*)&Bt[bB + ni * 1024 + c1];
    }
    QUAD8(0);
    LGKM0();
    BAR();                                  // (a)
    if (j + 2 < NK) { STAGE_A(j + 2); STAGE_B(j + 2); }
    QUAD8(1);
    if (j < NK - 2) { VM6(); } else { VM0(); }
    BAR();                                  // (b)
  }

#pragma unroll
  for (int ni = 0; ni < 2; ++ni) {
    const int col = (int)bn + w * 32 + ni * 16 + q;
    float bv;
    if (MODE == 4) {
      const int which = col >> 11, c = col & 2047;
      const float* bp = which == 0 ? b0 : (which == 1 ? b1 : b2);
      bv = bp[c];
    } else {
      bv = b0[col];
    }
#pragma unroll
    for (int mi = 0; mi < 4; ++mi)
#pragma unroll
      for (int r = 0; r < 4; ++r) {
        const long row = bm + mi * 16 + 4 * g + r;
        const float v = acc[mi][ni][r] + bv;
        if (MODE == 4) {
          const int which = col >> 11, c = col & 2047, head = c >> 7, d = c & 127;
          if (which == 0)      O0[((long)head * SEQ + row) * HD + d] = f2bu(v * QSCALE_L2E);
          else if (which == 1) O1[((long)head * SEQ + row) * HD + d] = f2bu(v);
          else                 O2[((long)head * HD + d) * SEQ + row] = f2bu(v);
        } else {
          Of[row * (long)N + col] = v;
        }
      }
  }
#undef STAGE_A
#undef STAGE_B
#undef QUAD8
}

// ---------------- flash attention v10: K/V double-buffer, 1 barrier/tile ----
// R22: R21's 8-wave split failed correctness (bug not identifiable -> dropped).
// This keeps the R19-proven 4-wave compute body VERBATIM and only changes the
// staging schedule: Kt[2]/Vt[2] double buffer (72KB dynamic LDS, still 2
// blocks/CU) with ONE __syncthreads per tile instead of two:
//   barrier -> compute tile t on buf[t&1] -> ds_write prefetched tile t+1
//   into buf[(t+1)&1] -> issue global loads for t+2.
// Hazards: writes to buf[(t+1)&1] at end of iter t are ordered after the last
// reads of that buffer (iter t-1) by the top-of-t barrier; reads of tile t
// follow the barrier that drains iter t-1's writes. Pt stays per-wave private
// (in-order LDS within a wave, R19-proven). vmcnt wait for kreg/vreg now sits
// at end-of-iter where the loads had a full compute span to land.
#define KVB 64
__global__ __launch_bounds__(256) void flash_attn(
    const unsigned short* __restrict__ Qb,
    const unsigned short* __restrict__ Kb,
    const unsigned short* __restrict__ VTb,
    unsigned short* __restrict__ attnb)      // [SEQ][HID] bf16
{
  // S (us): Kt[2] @0 (8192 each) | Vt[2] @16384 (8192 each) | Pt[4] @32768
  extern __shared__ unsigned short S[];      // 36864 us = 72KB
  const int tid = threadIdx.x;
  const int l = tid & 63, w = tid >> 6;
  const int g = l >> 4, q = l & 15;
  const int bid = blockIdx.x;
  const int jj = bid >> 3;
  const int h = ((bid & 7) << 1) | (jj >> 5);   // 2 heads per XCD (R19-proven)
  const int qb = jj & 31;
  const int qrow0 = qb * 64 + w * 16;

  unsigned short* Pw = S + 32768 + w * 1024;

  short8 qf[4];
#pragma unroll
  for (int dc = 0; dc < 4; ++dc)
    qf[dc] = *(const short8*)&Qb[((long)h * SEQ + qrow0 + q) * HD + dc * 32 + g * 8];

  f32x4 oacc[8] = {};
  float lsum[4] = {0.f, 0.f, 0.f, 0.f};

  const int kr = tid >> 4, kc16 = tid & 15;
  const int vr = tid >> 3, vc8 = tid & 7;
  const unsigned short* Kg = Kb + (long)h * SEQ * HD;
  const unsigned short* Vg = VTb + (long)h * HD * SEQ;

  short8 kreg[4], vreg[4];
  // tile 0 -> regs -> buf0
#pragma unroll
  for (int it = 0; it < 4; ++it) {
    kreg[it] = *(const short8*)&Kg[(long)(kr + it * 16) * HD + kc16 * 8];
    vreg[it] = *(const short8*)&Vg[(long)(vr + it * 32) * SEQ + vc8 * 8];
  }
#pragma unroll
  for (int it = 0; it < 4; ++it) {
    const int krow = kr + it * 16;
    *(short8*)&S[((krow * 256 + kc16 * 16) ^ ((krow & 7) << 4)) >> 1] = kreg[it];
    const int vrow = vr + it * 32;
    *(short8*)&S[16384 + (((vrow * 128 + vc8 * 16) ^ ((vrow & 7) << 4)) >> 1)] = vreg[it];
  }
  // prefetch tile 1
#pragma unroll
  for (int it = 0; it < 4; ++it) {
    kreg[it] = *(const short8*)&Kg[(long)(KVB + kr + it * 16) * HD + kc16 * 8];
    vreg[it] = *(const short8*)&Vg[(long)(vr + it * 32) * SEQ + KVB + vc8 * 8];
  }

  for (int t = 0; t < 32; ++t) {
    __syncthreads();                          // tile t's buffer visible to all
    const unsigned short* Kt = S + (t & 1) * 8192;
    const unsigned short* Vt = S + 16384 + (t & 1) * 8192;

    f32x4 sacc[4] = {};
    __builtin_amdgcn_s_setprio(1);
#pragma unroll
    for (int kc = 0; kc < 4; ++kc) {
      const int krow = kc * 16 + q;
      const int sw = (krow & 7) << 4;
#pragma unroll
      for (int dc = 0; dc < 4; ++dc) {
        short8 kf = *(const short8*)&Kt[((krow * 256 + dc * 64 + g * 16) ^ sw) >> 1];
        sacc[kc] = __builtin_amdgcn_mfma_f32_16x16x32_bf16(qf[dc], kf, sacc[kc], 0, 0, 0);
      }
    }
    __builtin_amdgcn_s_setprio(0);

    float p[4][4];
#pragma unroll
    for (int r = 0; r < 4; ++r) {
#pragma unroll
      for (int kc = 0; kc < 4; ++kc) p[kc][r] = exp2fast(sacc[kc][r]);
      lsum[r] += (p[0][r] + p[1][r]) + (p[2][r] + p[3][r]);
    }

#pragma unroll
    for (int r = 0; r < 4; ++r) {
      const int prow = 4 * g + r;
      const int sw = (prow & 7) << 4;
#pragma unroll
      for (int kc = 0; kc < 4; ++kc)
        Pw[((prow * 128 + (kc * 16 + q) * 2) ^ sw) >> 1] = f2bu_fast(p[kc][r]);
    }

    short8 pf[2];
    const int psw = (q & 7) << 4;
#pragma unroll
    for (int ks = 0; ks < 2; ++ks)
      pf[ks] = *(const short8*)&Pw[((q * 128 + ks * 64 + g * 16) ^ psw) >> 1];
    __builtin_amdgcn_s_setprio(1);
#pragma unroll
    for (int dt = 0; dt < 8; ++dt) {
      const int vrow = dt * 16 + q;
#pragma unroll
      for (int ks = 0; ks < 2; ++ks) {
        short8 vf = *(const short8*)&Vt[((vrow * 128 + ks * 64 + g * 16) ^ psw) >> 1];
        oacc[dt] = __builtin_amdgcn_mfma_f32_16x16x32_bf16(pf[ks], vf, oacc[dt], 0, 0, 0);
      }
    }
    __builtin_amdgcn_s_setprio(0);

    // write tile t+1 (prefetched) into the other buffer; issue loads for t+2
    if (t + 1 < 32) {
      unsigned short* Kn = S + ((t + 1) & 1) * 8192;
      unsigned short* Vn = S + 16384 + ((t + 1) & 1) * 8192;
#pragma unroll
      for (int it = 0; it < 4; ++it) {
        const int krow = kr + it * 16;
        *(short8*)&Kn[((krow * 256 + kc16 * 16) ^ ((krow & 7) << 4)) >> 1] = kreg[it];
        const int vrow = vr + it * 32;
        *(short8*)&Vn[((vrow * 128 + vc8 * 16) ^ ((vrow & 7) << 4)) >> 1] = vreg[it];
      }
      if (t + 2 < 32) {
        const int nkb = (t + 2) * KVB;
#pragma unroll
        for (int it = 0; it < 4; ++it) {
          kreg[it] = *(const short8*)&Kg[(long)(nkb + kr + it * 16) * HD + kc16 * 8];
          vreg[it] = *(const short8*)&Vg[(long)(vr + it * 32) * SEQ + nkb + vc8 * 8];
        }
      }
    }
  }

  // sum exp over the 16 q-lanes (KV columns live on q within each 16-lane grp)
#pragma unroll
  for (int off = 1; off < 16; off <<= 1)
#pragma unroll
    for (int r = 0; r < 4; ++r) lsum[r] += __shfl_xor(lsum[r], off);

  const float rl0 = 1.f / lsum[0], rl1 = 1.f / lsum[1];
  const float rl2 = 1.f / lsum[2], rl3 = 1.f / lsum[3];
#pragma unroll
  for (int dt = 0; dt < 8; ++dt) {
    const long colb = (long)h * HD + dt * 16 + q;
    attnb[(long)(qrow0 + 4 * g + 0) * HID + colb] = f2bu(oacc[dt][0] * rl0);
    attnb[(long)(qrow0 + 4 * g + 1) * HID + colb] = f2bu(oacc[dt][1] * rl1);
    attnb[(long)(qrow0 + 4 * g + 2) * HID + colb] = f2bu(oacc[dt][2] * rl2);
    attnb[(long)(qrow0 + 4 * g + 3) * HID + colb] = f2bu(oacc[dt][3] * rl3);
  }
}

extern "C" void kernel_launch(void* const* d_in, const int* in_sizes, int n_in,
                              void* d_out, int out_size, void* d_ws, size_t ws_size,
                              hipStream_t stream)
{
  const float* x  = (const float*)d_in[0];
  const float* wq = (const float*)d_in[1];
  const float* bq = (const float*)d_in[2];
  const float* wk = (const float*)d_in[3];
  const float* bk = (const float*)d_in[4];
  const float* wv = (const float*)d_in[5];
  const float* bv = (const float*)d_in[6];
  const float* wo = (const float*)d_in[7];
  const float* bo = (const float*)d_in[8];

  const long NEL = (long)HID * HID;
  unsigned short* Xb   = (unsigned short*)d_ws;
  unsigned short* Wqkv = Xb + NEL;
  unsigned short* Wob  = Wqkv + 3 * NEL;
  unsigned short* Qbuf = Wob + NEL;
  unsigned short* Kbuf = Qbuf + NEL;
  unsigned short* VTb  = Kbuf + NEL;
  unsigned short* Attn = VTb + NEL;

  // one-time opt-in for 72KB dynamic LDS (host-side, graph-capture safe;
  // same mechanism verified working in R15 at 128KB)
  static bool attrDone = false;
  if (!attrDone) {
    hipFuncSetAttribute(reinterpret_cast<const void*>(flash_attn),
                        hipFuncAttributeMaxDynamicSharedMemorySize, 73728);
    attrDone = true;
  }

  cvt_kernel<<<dim3(512, 5), 256, 0, stream>>>(
      x, wq, wk, wv, wo, Xb, Wqkv, Wqkv + NEL, Wqkv + 2 * NEL, Wob, (int)NEL);

  gemm97<4><<<dim3(48, 16), 256, 32768, stream>>>(
      Xb, Wqkv, bq, bk, bv, Qbuf, Kbuf, VTb, nullptr, SEQ, 3 * HID, HID);

  flash_attn<<<dim3(512), 256, 73728, stream>>>(Qbuf, Kbuf, VTb, Attn);

  gemm128<3><<<dim3(16, 32), 256, 49152, stream>>>(
      Attn, Wob, bo, nullptr, nullptr, nullptr, nullptr, nullptr,
      (float*)d_out, SEQ, HID, HID);
}